// Round 10
// baseline (148.699 us; speedup 1.0000x reference)
//
#include <hip/hip_runtime.h>
#include <hip/hip_bf16.h>
#include <math.h>

// BatchGATConv: N nodes, B=2 batches, DIN=128, H=4 heads, D=64, E edges.
// Dispatch plan (5 dispatches):
//   D0: memset deg
//   D1: hist (int4, 4 edges/thread) || prep WT          [independent]
//   D2: proj_mfma -> ftt[bh][node][64] f32 slices || striped scan
//   D3: scatter (CSR fill)
//   D4: agg: bh-sliced, XCD-affine (blockIdx%8=bh). Wave=(node,bh): 8 edge slots x
//       8 d8-lanes (32B f32 each), f32x4 vector FMA, LDS block epilogue.
//       Per-XCD working set = 5.1MB ft slice + 640KB el -> mostly L2-resident.

typedef unsigned short ushort;
typedef __attribute__((ext_vector_type(8))) unsigned short ushort8;
typedef __attribute__((ext_vector_type(8))) short short8v;
typedef __attribute__((ext_vector_type(4))) float f32x4;

constexpr int DIN = 128;
constexpr int B   = 2;
constexpr int H   = 4;
constexpr int D   = 64;
constexpr int HD  = H * D;      // 256
constexpr int BHD = B * HD;     // 512
constexpr int NCOL = 272;       // 256 + 16 (8 el/er cols + 8 zero pad)
constexpr int PREP_ELEMS  = NCOL * DIN;                 // 34816
constexpr int PREP_BLOCKS = (PREP_ELEMS + 255) / 256;   // 136
constexpr int SXS = 68;         // f32 LDS transpose row stride

__device__ __forceinline__ float leaky(float x) { return x >= 0.f ? x : 0.2f * x; }

__device__ __forceinline__ ushort f2bf(float f) {
    return __builtin_bit_cast(ushort, __float2bfloat16(f));
}

// ---------------- D1: hist || prep ----------------
__global__ __launch_bounds__(256) void hist_prep_kernel(
    const int* __restrict__ dst, int* __restrict__ deg, int E,
    const float* __restrict__ W, const float* __restrict__ attn_l,
    const float* __restrict__ attn_r, ushort* __restrict__ WT, int histBlocks)
{
    const int t = threadIdx.x;
    const int b = blockIdx.x;
    if (b < histBlocks) {
        int e4 = (b * 256 + t) * 4;
        if (e4 + 3 < E) {
            int4 dd = *(const int4*)(dst + e4);
            atomicAdd(&deg[dd.x], 1); atomicAdd(&deg[dd.y], 1);
            atomicAdd(&deg[dd.z], 1); atomicAdd(&deg[dd.w], 1);
        } else {
            for (int e = e4; e < E; ++e) atomicAdd(&deg[dst[e]], 1);
        }
        return;
    }
    int id = (b - histBlocks) * 256 + t;
    if (id >= PREP_ELEMS) return;
    int c = id >> 7, k = id & 127;
    float v;
    if (c < 256) {
        v = W[k * HD + c];
    } else if (c < 264) {
        int j = c - 256, h = j & 3;
        const float* av = (j < 4 ? attn_l : attn_r) + h * D;
        const float* wp = W + k * HD + h * D;
        float s = 0.f;
        for (int d = 0; d < D; ++d) s = fmaf(wp[d], av[d], s);
        v = s;
    } else {
        v = 0.f;
    }
    WT[c * DIN + k] = f2bf(v);
}

// ---------------- striped coalesced single-block scan ----------------
__device__ void scan_body(const int* __restrict__ deg, int* __restrict__ offs,
                          int* __restrict__ cursor, int n)
{
    __shared__ int wcarry[4];
    const int t = threadIdx.x;
    const int lane = t & 63;
    const int wid = t >> 6;
    int carry = 0;
    const int nstripes = (n + 1023) >> 10;
    for (int s = 0; s < nstripes; ++s) {
        const int base = (s << 10) + t * 4;
        int4 d = make_int4(0, 0, 0, 0);
        if (base + 3 < n) {
            d = *(const int4*)(deg + base);
        } else {
            if (base     < n) d.x = deg[base];
            if (base + 1 < n) d.y = deg[base + 1];
            if (base + 2 < n) d.z = deg[base + 2];
        }
        const int sum4 = (d.x + d.y) + (d.z + d.w);
        int inc = sum4;
#pragma unroll
        for (int o = 1; o < 64; o <<= 1) {
            int v = __shfl_up(inc, o, 64);
            if (lane >= o) inc += v;
        }
        if (lane == 63) wcarry[wid] = inc;
        __syncthreads();
        int wpre = carry;
#pragma unroll
        for (int k = 0; k < 4; ++k) if (k < wid) wpre += wcarry[k];
        const int e0 = wpre + inc - sum4;
        int4 ov;
        ov.x = e0; ov.y = e0 + d.x; ov.z = ov.y + d.y; ov.w = ov.z + d.z;
        if (base + 3 < n) {
            *(int4*)(offs + base) = ov;
            *(int4*)(cursor + base) = ov;
        } else {
            if (base     < n) { offs[base]     = ov.x; cursor[base]     = ov.x; }
            if (base + 1 < n) { offs[base + 1] = ov.y; cursor[base + 1] = ov.y; }
            if (base + 2 < n) { offs[base + 2] = ov.z; cursor[base + 2] = ov.z; }
        }
        carry += (wcarry[0] + wcarry[1]) + (wcarry[2] + wcarry[3]);
        __syncthreads();
    }
    if (t == 0) offs[n] = carry;
}

// ---------------- D2: proj_mfma || scan ----------------
// 256 threads = 4 waves. Block tile: 64 rows x 272 cols, K=128 (R % 64 == 0).
// ft stored as ftt[bh][node][64] f32 (bh = b*4+h) for bh-sliced aggregation.
__global__ __launch_bounds__(256) void proj_scan_kernel(
    const float* __restrict__ feat, const ushort* __restrict__ WT,
    float* __restrict__ ftt, float* __restrict__ el, float* __restrict__ er,
    const int* __restrict__ deg, int* __restrict__ offs, int* __restrict__ cursor,
    int N, int nTiles)
{
    if ((int)blockIdx.x >= nTiles) {
        scan_body(deg, offs, cursor, N);
        return;
    }
    __shared__ float sxp[4][2][16][SXS];   // 34.8 KB
    const int t = threadIdx.x;
    const int w = t >> 6;
    const int lane = t & 63;
    const int lr = lane & 15;
    const int lk = lane >> 4;

    short8v bfrag[4][4];
#pragma unroll
    for (int ct = 0; ct < 4; ++ct) {
        const int col = w * 64 + ct * 16 + lr;
#pragma unroll
        for (int ks = 0; ks < 4; ++ks)
            bfrag[ct][ks] = *(const short8v*)&WT[col * DIN + ks * 32 + lk * 8];
    }
    short8v efrag[4];
#pragma unroll
    for (int ks = 0; ks < 4; ++ks)
        efrag[ks] = *(const short8v*)&WT[(256 + lr) * DIN + ks * 32 + lk * 8];

    const int row0 = blockIdx.x * 64;
    const int rrow = lane >> 2;          // readback row 0..15
    const int sg   = lane & 3;           // 16-float segment 0..3

    auto loadA = [&](int rt, short8v aout[4]) {
        const float* fp = feat + (size_t)(row0 + rt * 16 + lr) * DIN + lk * 8;
#pragma unroll
        for (int ks = 0; ks < 4; ++ks) {
            f32x4 x0 = *(const f32x4*)(fp + ks * 32);
            f32x4 x1 = *(const f32x4*)(fp + ks * 32 + 4);
            short8v v;
            v[0] = (short)f2bf(x0[0]); v[1] = (short)f2bf(x0[1]);
            v[2] = (short)f2bf(x0[2]); v[3] = (short)f2bf(x0[3]);
            v[4] = (short)f2bf(x1[0]); v[5] = (short)f2bf(x1[1]);
            v[6] = (short)f2bf(x1[2]); v[7] = (short)f2bf(x1[3]);
            aout[ks] = v;
        }
    };

    short8v aP[4], aN[4];
    loadA(0, aP);

#pragma unroll
    for (int rt = 0; rt < 4; ++rt) {
        if (rt < 3) loadA(rt + 1, aN);

        f32x4 acc[4] = {{0.f,0.f,0.f,0.f},{0.f,0.f,0.f,0.f},{0.f,0.f,0.f,0.f},{0.f,0.f,0.f,0.f}};
#pragma unroll
        for (int ct = 0; ct < 4; ++ct)
#pragma unroll
            for (int ks = 0; ks < 4; ++ks)
                acc[ct] = __builtin_amdgcn_mfma_f32_16x16x32_bf16(aP[ks], bfrag[ct][ks], acc[ct], 0, 0, 0);

        // transpose via wave-private LDS (double-buffered, f32)
        float (* __restrict__ sw)[SXS] = sxp[w][rt & 1];
#pragma unroll
        for (int ct = 0; ct < 4; ++ct)
#pragma unroll
            for (int r = 0; r < 4; ++r)
                sw[lk * 4 + r][ct * 16 + lr] = acc[ct][r];
        __builtin_amdgcn_wave_barrier();
        f32x4 o[4];
#pragma unroll
        for (int k = 0; k < 4; ++k)
            o[k] = *(const f32x4*)&sw[rrow][sg * 16 + k * 4];
        // row -> (node, batch); this wave's 64-col segment is head h == w
        const int row = row0 + rt * 16 + rrow;
        const int nn = row >> 1;            // node  (row = n*B + b, B=2)
        const int bb = row & 1;             // batch
        float* gp = ftt + ((size_t)(bb * 4 + w) * N + nn) * 64 + sg * 16;
#pragma unroll
        for (int k = 0; k < 4; ++k)
            *(f32x4*)(gp + k * 4) = o[k];

        if (rt == w) {
            f32x4 acce = {0.f, 0.f, 0.f, 0.f};
#pragma unroll
            for (int ks = 0; ks < 4; ++ks)
                acce = __builtin_amdgcn_mfma_f32_16x16x32_bf16(aP[ks], efrag[ks], acce, 0, 0, 0);
#pragma unroll
            for (int r = 0; r < 4; ++r) {
                const int row2 = row0 + rt * 16 + lk * 4 + r;
                if (lr < 4)       el[row2 * 4 + lr]       = acce[r];
                else if (lr < 8)  er[row2 * 4 + (lr - 4)] = acce[r];
            }
        }

#pragma unroll
        for (int ks = 0; ks < 4; ++ks) aP[ks] = aN[ks];
    }
}

// ---------------- D3: scatter ----------------
__global__ __launch_bounds__(256) void scatter_kernel(
    const int* __restrict__ dst, const int* __restrict__ src,
    int* __restrict__ cursor, int* __restrict__ esrc, int E)
{
    int e4 = (blockIdx.x * 256 + threadIdx.x) * 4;
    if (e4 + 3 < E) {
        int4 dd = *(const int4*)(dst + e4);
        int4 ss = *(const int4*)(src + e4);
        int p0 = atomicAdd(&cursor[dd.x], 1); esrc[p0] = ss.x;
        int p1 = atomicAdd(&cursor[dd.y], 1); esrc[p1] = ss.y;
        int p2 = atomicAdd(&cursor[dd.z], 1); esrc[p2] = ss.z;
        int p3 = atomicAdd(&cursor[dd.w], 1); esrc[p3] = ss.w;
    } else {
        for (int e = e4; e < E; ++e) {
            int pos = atomicAdd(&cursor[dst[e]], 1);
            esrc[pos] = src[e];
        }
    }
}

// ---------------- D4: agg (bh-sliced, XCD-affine, f32, LDS epilogue) ----------------
// blockIdx%8 = bh (XCD round-robin), blockIdx/8 = node group of 4 (one per wave).
// Lane g=lane>>3 is the edge slot, d8=lane&7 covers floats d8*8..d8*8+7 (2 float4).
__global__ __launch_bounds__(256) void agg_kernel(
    const float* __restrict__ ftt, const float* __restrict__ el,
    const float* __restrict__ er, const int* __restrict__ offs,
    const int* __restrict__ esrc, float* __restrict__ out, int N)
{
    __shared__ float red[4][8][64];   // 8 KB: [wave][g][elem]
    const int t = threadIdx.x;
    const int bh = blockIdx.x & 7;
    const int nbase = (blockIdx.x >> 3) * 4;
    const int wv = t >> 6;
    const int n = nbase + wv;
    const bool valid = (n < N);
    const int lane = t & 63;
    const int g  = lane >> 3;   // edge slot 0..7
    const int d8 = lane & 7;    // 32B segment 0..7
    const int beg = valid ? offs[n] : 0;
    const int end = valid ? offs[n + 1] : 0;
    const float erd = valid ? er[n * 8 + bh] : 0.f;
    const f32x4* __restrict__ fv = (const f32x4*)(ftt + (size_t)bh * N * 64);

    f32x4 acc0 = {0.f, 0.f, 0.f, 0.f};
    f32x4 acc1 = {0.f, 0.f, 0.f, 0.f};
    float dsum = 0.f;

    int i = beg + g;
    for (; i + 8 < end; i += 16) {   // 2 edges per slot in flight
        int s0 = esrc[i];
        int s1 = esrc[i + 8];
        float x0 = el[(size_t)s0 * 8 + bh];
        float x1 = el[(size_t)s1 * 8 + bh];
        f32x4 a0 = fv[(size_t)s0 * 16 + d8 * 2];
        f32x4 b0 = fv[(size_t)s0 * 16 + d8 * 2 + 1];
        f32x4 a1 = fv[(size_t)s1 * 16 + d8 * 2];
        f32x4 b1 = fv[(size_t)s1 * 16 + d8 * 2 + 1];
        float w0 = __expf(leaky(x0 + erd));
        float w1 = __expf(leaky(x1 + erd));
        dsum += w0 + w1;
        acc0 += a0 * w0; acc1 += b0 * w0;
        acc0 += a1 * w1; acc1 += b1 * w1;
    }
    if (i < end) {
        int s0 = esrc[i];
        float w0 = __expf(leaky(el[(size_t)s0 * 8 + bh] + erd));
        f32x4 a0 = fv[(size_t)s0 * 16 + d8 * 2];
        f32x4 b0 = fv[(size_t)s0 * 16 + d8 * 2 + 1];
        dsum += w0;
        acc0 += a0 * w0; acc1 += b0 * w0;
    }

    // dsum: identical across d8 within a slot; xor-reduce over slot bits 3..5
#pragma unroll
    for (int o = 8; o < 64; o <<= 1)
        dsum += __shfl_xor(dsum, o, 64);

    // stage g-partials to LDS
    *(f32x4*)&red[wv][g][d8 * 8]     = acc0;
    *(f32x4*)&red[wv][g][d8 * 8 + 4] = acc1;
    __syncthreads();

    // finish: thread (wv, e) sums 8 partials, scales, stores coalesced
    const int e = lane;
    float s = 0.f;
#pragma unroll
    for (int gg = 0; gg < 8; ++gg) s += red[wv][gg][e];
    if (valid) {
        const float sc = (end > beg) ? (1.f / dsum) : 0.f;
        out[(size_t)n * BHD + bh * 64 + e] = leaky(s * sc);
    }
}

extern "C" void kernel_launch(void* const* d_in, const int* in_sizes, int n_in,
                              void* d_out, int out_size, void* d_ws, size_t ws_size,
                              hipStream_t stream)
{
    const float* feat   = (const float*)d_in[0];
    const float* W      = (const float*)d_in[1];
    const float* attn_l = (const float*)d_in[2];
    const float* attn_r = (const float*)d_in[3];
    const int*   src    = (const int*)d_in[4];
    const int*   dst    = (const int*)d_in[5];
    float* out = (float*)d_out;

    const int N = in_sizes[0] / (B * DIN);
    const int E = in_sizes[4];
    const int R = N * B;
    const int nTiles = R / 64;                    // 625 for R=40000 (R % 64 == 0)
    const int histBlocks = (E / 4 + 255) / 256;
    const int edgeBlocks = histBlocks;

    auto align_up = [](size_t x) { return (x + 255) & ~(size_t)255; };
    size_t off = 0;
    char* base = (char*)d_ws;
    float* ftt  = (float*)(base + off); off += align_up((size_t)R * HD * sizeof(float));
    float* el   = (float*)(base + off); off += align_up((size_t)R * H * sizeof(float));
    float* er   = (float*)(base + off); off += align_up((size_t)R * H * sizeof(float));
    ushort* WT  = (ushort*)(base + off); off += align_up((size_t)NCOL * DIN * sizeof(ushort));
    int* deg    = (int*)(base + off); off += align_up((size_t)N * sizeof(int));
    int* offs   = (int*)(base + off); off += align_up((size_t)(N + 1) * sizeof(int));
    int* cursor = (int*)(base + off); off += align_up((size_t)N * sizeof(int));
    int* esrc   = (int*)(base + off); off += align_up((size_t)E * sizeof(int));
    (void)ws_size; (void)n_in; (void)out_size;

    hipMemsetAsync(deg, 0, (size_t)N * sizeof(int), stream);

    hist_prep_kernel<<<histBlocks + PREP_BLOCKS, 256, 0, stream>>>(
        dst, deg, E, W, attn_l, attn_r, WT, histBlocks);
    proj_scan_kernel<<<nTiles + 1, 256, 0, stream>>>(
        feat, WT, ftt, el, er, deg, offs, cursor, N, nTiles);
    scatter_kernel<<<edgeBlocks, 256, 0, stream>>>(dst, src, cursor, esrc, E);
    agg_kernel<<<8 * ((N + 3) / 4), 256, 0, stream>>>(ftt, el, er, offs, esrc, out, N);
}

// Round 11
// 137.593 us; speedup vs baseline: 1.0807x; 1.0807x over previous
//
#include <hip/hip_runtime.h>
#include <hip/hip_bf16.h>
#include <math.h>

// BatchGATConv: N nodes, B=2 batches, DIN=128, H=4 heads, D=64, E edges.
// Dispatch plan (5 dispatches):
//   D0: memset deg
//   D1: hist (int4, 4 edges/thread) || prep WT          [independent]
//   D2: proj_mfma -> ftt[bh][node][64] bf16 slices || striped scan
//   D3: scatter (CSR fill)
//   D4: agg: bh-sliced, XCD-affine (blockIdx%8=bh), persistent grid-stride waves,
//       8 edge slots x 8 d8-lanes, 32-bit addressing throughout, shuffle epilogue.
//       Per-XCD working set = 2.56MB bf16 ft slice + 640KB el -> L2-resident.

typedef unsigned short ushort;
typedef __attribute__((ext_vector_type(8))) unsigned short ushort8;
typedef __attribute__((ext_vector_type(8))) short short8v;
typedef __attribute__((ext_vector_type(4))) float f32x4;

constexpr int DIN = 128;
constexpr int B   = 2;
constexpr int H   = 4;
constexpr int D   = 64;
constexpr int HD  = H * D;      // 256
constexpr int BHD = B * HD;     // 512
constexpr int NCOL = 272;       // 256 + 16 (8 el/er cols + 8 zero pad)
constexpr int PREP_ELEMS  = NCOL * DIN;                 // 34816
constexpr int PREP_BLOCKS = (PREP_ELEMS + 255) / 256;   // 136
constexpr int SXS = 72;         // LDS transpose row stride (ushorts)

__device__ __forceinline__ float leaky(float x) { return x >= 0.f ? x : 0.2f * x; }

__device__ __forceinline__ ushort f2bf(float f) {
    return __builtin_bit_cast(ushort, __float2bfloat16(f));
}
__device__ __forceinline__ float bf2f(ushort v) {
    return __uint_as_float(((unsigned int)v) << 16);
}

// ---------------- D1: hist || prep ----------------
__global__ __launch_bounds__(256) void hist_prep_kernel(
    const int* __restrict__ dst, int* __restrict__ deg, int E,
    const float* __restrict__ W, const float* __restrict__ attn_l,
    const float* __restrict__ attn_r, ushort* __restrict__ WT, int histBlocks)
{
    const int t = threadIdx.x;
    const int b = blockIdx.x;
    if (b < histBlocks) {
        int e4 = (b * 256 + t) * 4;
        if (e4 + 3 < E) {
            int4 dd = *(const int4*)(dst + e4);
            atomicAdd(&deg[dd.x], 1); atomicAdd(&deg[dd.y], 1);
            atomicAdd(&deg[dd.z], 1); atomicAdd(&deg[dd.w], 1);
        } else {
            for (int e = e4; e < E; ++e) atomicAdd(&deg[dst[e]], 1);
        }
        return;
    }
    int id = (b - histBlocks) * 256 + t;
    if (id >= PREP_ELEMS) return;
    int c = id >> 7, k = id & 127;
    float v;
    if (c < 256) {
        v = W[k * HD + c];
    } else if (c < 264) {
        int j = c - 256, h = j & 3;
        const float* av = (j < 4 ? attn_l : attn_r) + h * D;
        const float* wp = W + k * HD + h * D;
        float s = 0.f;
        for (int d = 0; d < D; ++d) s = fmaf(wp[d], av[d], s);
        v = s;
    } else {
        v = 0.f;
    }
    WT[c * DIN + k] = f2bf(v);
}

// ---------------- striped coalesced single-block scan ----------------
__device__ void scan_body(const int* __restrict__ deg, int* __restrict__ offs,
                          int* __restrict__ cursor, int n)
{
    __shared__ int wcarry[4];
    const int t = threadIdx.x;
    const int lane = t & 63;
    const int wid = t >> 6;
    int carry = 0;
    const int nstripes = (n + 1023) >> 10;
    for (int s = 0; s < nstripes; ++s) {
        const int base = (s << 10) + t * 4;
        int4 d = make_int4(0, 0, 0, 0);
        if (base + 3 < n) {
            d = *(const int4*)(deg + base);
        } else {
            if (base     < n) d.x = deg[base];
            if (base + 1 < n) d.y = deg[base + 1];
            if (base + 2 < n) d.z = deg[base + 2];
        }
        const int sum4 = (d.x + d.y) + (d.z + d.w);
        int inc = sum4;
#pragma unroll
        for (int o = 1; o < 64; o <<= 1) {
            int v = __shfl_up(inc, o, 64);
            if (lane >= o) inc += v;
        }
        if (lane == 63) wcarry[wid] = inc;
        __syncthreads();
        int wpre = carry;
#pragma unroll
        for (int k = 0; k < 4; ++k) if (k < wid) wpre += wcarry[k];
        const int e0 = wpre + inc - sum4;
        int4 ov;
        ov.x = e0; ov.y = e0 + d.x; ov.z = ov.y + d.y; ov.w = ov.z + d.z;
        if (base + 3 < n) {
            *(int4*)(offs + base) = ov;
            *(int4*)(cursor + base) = ov;
        } else {
            if (base     < n) { offs[base]     = ov.x; cursor[base]     = ov.x; }
            if (base + 1 < n) { offs[base + 1] = ov.y; cursor[base + 1] = ov.y; }
            if (base + 2 < n) { offs[base + 2] = ov.z; cursor[base + 2] = ov.z; }
        }
        carry += (wcarry[0] + wcarry[1]) + (wcarry[2] + wcarry[3]);
        __syncthreads();
    }
    if (t == 0) offs[n] = carry;
}

// ---------------- D2: proj_mfma || scan ----------------
// 256 threads = 4 waves. Block tile: 64 rows x 272 cols, K=128 (R % 64 == 0).
// ft stored as ftt[bh][node][64] bf16 (bh = b*4+h) for bh-sliced aggregation.
__global__ __launch_bounds__(256) void proj_scan_kernel(
    const float* __restrict__ feat, const ushort* __restrict__ WT,
    ushort* __restrict__ ftt, float* __restrict__ el, float* __restrict__ er,
    const int* __restrict__ deg, int* __restrict__ offs, int* __restrict__ cursor,
    int N, int nTiles)
{
    if ((int)blockIdx.x >= nTiles) {
        scan_body(deg, offs, cursor, N);
        return;
    }
    __shared__ ushort sxp[4][2][16][SXS];
    const int t = threadIdx.x;
    const int w = t >> 6;
    const int lane = t & 63;
    const int lr = lane & 15;
    const int lk = lane >> 4;

    short8v bfrag[4][4];
#pragma unroll
    for (int ct = 0; ct < 4; ++ct) {
        const int col = w * 64 + ct * 16 + lr;
#pragma unroll
        for (int ks = 0; ks < 4; ++ks)
            bfrag[ct][ks] = *(const short8v*)&WT[col * DIN + ks * 32 + lk * 8];
    }
    short8v efrag[4];
#pragma unroll
    for (int ks = 0; ks < 4; ++ks)
        efrag[ks] = *(const short8v*)&WT[(256 + lr) * DIN + ks * 32 + lk * 8];

    const int row0 = blockIdx.x * 64;
    const int rrow = lane >> 2;
    const int seg  = lane & 3;

    auto loadA = [&](int rt, short8v aout[4]) {
        const float* fp = feat + (size_t)(row0 + rt * 16 + lr) * DIN + lk * 8;
#pragma unroll
        for (int ks = 0; ks < 4; ++ks) {
            f32x4 x0 = *(const f32x4*)(fp + ks * 32);
            f32x4 x1 = *(const f32x4*)(fp + ks * 32 + 4);
            short8v v;
            v[0] = (short)f2bf(x0[0]); v[1] = (short)f2bf(x0[1]);
            v[2] = (short)f2bf(x0[2]); v[3] = (short)f2bf(x0[3]);
            v[4] = (short)f2bf(x1[0]); v[5] = (short)f2bf(x1[1]);
            v[6] = (short)f2bf(x1[2]); v[7] = (short)f2bf(x1[3]);
            aout[ks] = v;
        }
    };

    short8v aP[4], aN[4];
    loadA(0, aP);

#pragma unroll
    for (int rt = 0; rt < 4; ++rt) {
        if (rt < 3) loadA(rt + 1, aN);

        f32x4 acc[4] = {{0.f,0.f,0.f,0.f},{0.f,0.f,0.f,0.f},{0.f,0.f,0.f,0.f},{0.f,0.f,0.f,0.f}};
#pragma unroll
        for (int ct = 0; ct < 4; ++ct)
#pragma unroll
            for (int ks = 0; ks < 4; ++ks)
                acc[ct] = __builtin_amdgcn_mfma_f32_16x16x32_bf16(aP[ks], bfrag[ct][ks], acc[ct], 0, 0, 0);

        ushort (* __restrict__ sw)[SXS] = sxp[w][rt & 1];
#pragma unroll
        for (int ct = 0; ct < 4; ++ct)
#pragma unroll
            for (int r = 0; r < 4; ++r)
                sw[lk * 4 + r][ct * 16 + lr] = f2bf(acc[ct][r]);
        __builtin_amdgcn_wave_barrier();
        ushort8 o0 = *(const ushort8*)&sw[rrow][seg * 16];
        ushort8 o1 = *(const ushort8*)&sw[rrow][seg * 16 + 8];
        // row -> (node, batch); this wave's 64-col segment is head h == w
        const int row = row0 + rt * 16 + rrow;
        const int nn = row >> 1;            // node  (row = n*B + b, B=2)
        const int bb = row & 1;             // batch
        ushort* gp = ftt + ((size_t)(bb * 4 + w) * N + nn) * 64 + seg * 16;
        *(ushort8*)gp = o0;
        *(ushort8*)(gp + 8) = o1;

        if (rt == w) {
            f32x4 acce = {0.f, 0.f, 0.f, 0.f};
#pragma unroll
            for (int ks = 0; ks < 4; ++ks)
                acce = __builtin_amdgcn_mfma_f32_16x16x32_bf16(aP[ks], efrag[ks], acce, 0, 0, 0);
#pragma unroll
            for (int r = 0; r < 4; ++r) {
                const int row2 = row0 + rt * 16 + lk * 4 + r;
                if (lr < 4)       el[row2 * 4 + lr]       = acce[r];
                else if (lr < 8)  er[row2 * 4 + (lr - 4)] = acce[r];
            }
        }

#pragma unroll
        for (int ks = 0; ks < 4; ++ks) aP[ks] = aN[ks];
    }
}

// ---------------- D3: scatter ----------------
__global__ __launch_bounds__(256) void scatter_kernel(
    const int* __restrict__ dst, const int* __restrict__ src,
    int* __restrict__ cursor, int* __restrict__ esrc, int E)
{
    int e4 = (blockIdx.x * 256 + threadIdx.x) * 4;
    if (e4 + 3 < E) {
        int4 dd = *(const int4*)(dst + e4);
        int4 ss = *(const int4*)(src + e4);
        int p0 = atomicAdd(&cursor[dd.x], 1); esrc[p0] = ss.x;
        int p1 = atomicAdd(&cursor[dd.y], 1); esrc[p1] = ss.y;
        int p2 = atomicAdd(&cursor[dd.z], 1); esrc[p2] = ss.z;
        int p3 = atomicAdd(&cursor[dd.w], 1); esrc[p3] = ss.w;
    } else {
        for (int e = e4; e < E; ++e) {
            int pos = atomicAdd(&cursor[dst[e]], 1);
            esrc[pos] = src[e];
        }
    }
}

// ---------------- D4: agg (bh-sliced, XCD-affine, persistent, 32-bit addr) ----------------
// blockIdx&7 = bh plane (XCD round-robin); waves grid-stride over nodes.
// Lane g=lane>>3 is the edge slot, d8=lane&7 the 16B segment of the 128B slice.
__global__ __launch_bounds__(256) void agg_kernel(
    const ushort* __restrict__ ftt, const float* __restrict__ el,
    const float* __restrict__ er, const int* __restrict__ offs,
    const int* __restrict__ esrc, float* __restrict__ out, int N)
{
    const int t = threadIdx.x;
    const int bh = blockIdx.x & 7;
    const int wv = t >> 6;
    const int lane = t & 63;
    const int g  = lane >> 3;   // edge slot 0..7
    const int d8 = lane & 7;    // 16B segment 0..7
    const int nWavesPerPlane = (gridDim.x >> 3) * 4;
    const ushort8* __restrict__ fpl = (const ushort8*)(ftt + bh * (N * 64));  // 32-bit offset
    const float* __restrict__ elb = el + bh;

    for (int n = (blockIdx.x >> 3) * 4 + wv; n < N; n += nWavesPerPlane) {
        const int beg = offs[n];
        const int end = offs[n + 1];
        const float erd = er[n * 8 + bh];

        float acc[8];
#pragma unroll
        for (int j = 0; j < 8; ++j) acc[j] = 0.f;
        float dsum = 0.f;

        int i = beg + g;
        for (; i + 8 < end; i += 16) {   // 2 edges per slot in flight
            int s0 = esrc[i];
            int s1 = esrc[i + 8];
            float x0 = elb[s0 * 8];
            float x1 = elb[s1 * 8];
            ushort8 v0 = fpl[s0 * 8 + d8];
            ushort8 v1 = fpl[s1 * 8 + d8];
            float w0 = __expf(leaky(x0 + erd));
            float w1 = __expf(leaky(x1 + erd));
            dsum += w0 + w1;
#pragma unroll
            for (int j = 0; j < 8; ++j)
                acc[j] += w0 * bf2f(v0[j]) + w1 * bf2f(v1[j]);
        }
        if (i < end) {
            int s0 = esrc[i];
            float w0 = __expf(leaky(elb[s0 * 8] + erd));
            ushort8 v0 = fpl[s0 * 8 + d8];
            dsum += w0;
#pragma unroll
            for (int j = 0; j < 8; ++j) acc[j] = fmaf(w0, bf2f(v0[j]), acc[j]);
        }

        // reduce across the 8 edge-slot groups (lane bits 3..5)
#pragma unroll
        for (int o = 8; o < 64; o <<= 1) {
            dsum += __shfl_xor(dsum, o, 64);
#pragma unroll
            for (int j = 0; j < 8; ++j) acc[j] += __shfl_xor(acc[j], o, 64);
        }

        if (g == 0) {
            const float sc = (end > beg) ? (1.f / dsum) : 0.f;
            float4 o0, o1;
            o0.x = leaky(acc[0] * sc); o0.y = leaky(acc[1] * sc);
            o0.z = leaky(acc[2] * sc); o0.w = leaky(acc[3] * sc);
            o1.x = leaky(acc[4] * sc); o1.y = leaky(acc[5] * sc);
            o1.z = leaky(acc[6] * sc); o1.w = leaky(acc[7] * sc);
            float* op = out + n * BHD + bh * 64 + d8 * 8;   // 32-bit (max ~10.2M floats)
            *(float4*)op = o0;
            *(float4*)(op + 4) = o1;
        }
    }
}

extern "C" void kernel_launch(void* const* d_in, const int* in_sizes, int n_in,
                              void* d_out, int out_size, void* d_ws, size_t ws_size,
                              hipStream_t stream)
{
    const float* feat   = (const float*)d_in[0];
    const float* W      = (const float*)d_in[1];
    const float* attn_l = (const float*)d_in[2];
    const float* attn_r = (const float*)d_in[3];
    const int*   src    = (const int*)d_in[4];
    const int*   dst    = (const int*)d_in[5];
    float* out = (float*)d_out;

    const int N = in_sizes[0] / (B * DIN);
    const int E = in_sizes[4];
    const int R = N * B;
    const int nTiles = R / 64;                    // 625 for R=40000 (R % 64 == 0)
    const int histBlocks = (E / 4 + 255) / 256;
    const int edgeBlocks = histBlocks;

    auto align_up = [](size_t x) { return (x + 255) & ~(size_t)255; };
    size_t off = 0;
    char* base = (char*)d_ws;
    ushort* ftt = (ushort*)(base + off); off += align_up((size_t)R * HD * sizeof(ushort));
    float* el   = (float*)(base + off); off += align_up((size_t)R * H * sizeof(float));
    float* er   = (float*)(base + off); off += align_up((size_t)R * H * sizeof(float));
    ushort* WT  = (ushort*)(base + off); off += align_up((size_t)NCOL * DIN * sizeof(ushort));
    int* deg    = (int*)(base + off); off += align_up((size_t)N * sizeof(int));
    int* offs   = (int*)(base + off); off += align_up((size_t)(N + 1) * sizeof(int));
    int* cursor = (int*)(base + off); off += align_up((size_t)N * sizeof(int));
    int* esrc   = (int*)(base + off); off += align_up((size_t)E * sizeof(int));
    (void)ws_size; (void)n_in; (void)out_size;

    hipMemsetAsync(deg, 0, (size_t)N * sizeof(int), stream);

    hist_prep_kernel<<<histBlocks + PREP_BLOCKS, 256, 0, stream>>>(
        dst, deg, E, W, attn_l, attn_r, WT, histBlocks);
    proj_scan_kernel<<<nTiles + 1, 256, 0, stream>>>(
        feat, WT, ftt, el, er, deg, offs, cursor, N, nTiles);
    scatter_kernel<<<edgeBlocks, 256, 0, stream>>>(dst, src, cursor, esrc, E);
    agg_kernel<<<2048, 256, 0, stream>>>(ftt, el, er, offs, esrc, out, N);
}

// Round 12
// 120.858 us; speedup vs baseline: 1.2304x; 1.1385x over previous
//
#include <hip/hip_runtime.h>
#include <hip/hip_bf16.h>
#include <math.h>

// BatchGATConv: N nodes, B=2 batches, DIN=128, H=4 heads, D=64, E edges.
// Dispatch plan (5 dispatches):
//   D0: memset deg
//   D1: hist (int4, 4 edges/thread) || prep WT          [independent]
//   D2: proj_mfma (PERSISTENT blocks: B-frags loaded once, 2 tiles each) || scan
//   D3: scatter (int4 loads, atomic cursors)
//   D4: agg (R6 structure: wave=node, 8-edge slots, full 512-dim row; loads reordered)

typedef unsigned short ushort;
typedef __attribute__((ext_vector_type(8))) unsigned short ushort8;
typedef __attribute__((ext_vector_type(8))) short short8v;
typedef __attribute__((ext_vector_type(4))) float f32x4;

constexpr int DIN = 128;
constexpr int B   = 2;
constexpr int H   = 4;
constexpr int D   = 64;
constexpr int HD  = H * D;      // 256
constexpr int BHD = B * HD;     // 512
constexpr int NCOL = 272;       // 256 + 16 (8 el/er cols + 8 zero pad)
constexpr int PREP_ELEMS  = NCOL * DIN;                 // 34816
constexpr int PREP_BLOCKS = (PREP_ELEMS + 255) / 256;   // 136
constexpr int SXS = 72;         // LDS transpose row stride (ushorts)

__device__ __forceinline__ float leaky(float x) { return x >= 0.f ? x : 0.2f * x; }

__device__ __forceinline__ ushort f2bf(float f) {
    return __builtin_bit_cast(ushort, __float2bfloat16(f));
}
__device__ __forceinline__ float bf2f(ushort v) {
    return __uint_as_float(((unsigned int)v) << 16);
}

// ---------------- D1: hist || prep ----------------
__global__ __launch_bounds__(256) void hist_prep_kernel(
    const int* __restrict__ dst, int* __restrict__ deg, int E,
    const float* __restrict__ W, const float* __restrict__ attn_l,
    const float* __restrict__ attn_r, ushort* __restrict__ WT, int histBlocks)
{
    const int t = threadIdx.x;
    const int b = blockIdx.x;
    if (b < histBlocks) {
        int e4 = (b * 256 + t) * 4;
        if (e4 + 3 < E) {
            int4 dd = *(const int4*)(dst + e4);
            atomicAdd(&deg[dd.x], 1); atomicAdd(&deg[dd.y], 1);
            atomicAdd(&deg[dd.z], 1); atomicAdd(&deg[dd.w], 1);
        } else {
            for (int e = e4; e < E; ++e) atomicAdd(&deg[dst[e]], 1);
        }
        return;
    }
    int id = (b - histBlocks) * 256 + t;
    if (id >= PREP_ELEMS) return;
    int c = id >> 7, k = id & 127;
    float v;
    if (c < 256) {
        v = W[k * HD + c];
    } else if (c < 264) {
        int j = c - 256, h = j & 3;
        const float* av = (j < 4 ? attn_l : attn_r) + h * D;
        const float* wp = W + k * HD + h * D;
        float s = 0.f;
        for (int d = 0; d < D; ++d) s = fmaf(wp[d], av[d], s);
        v = s;
    } else {
        v = 0.f;
    }
    WT[c * DIN + k] = f2bf(v);
}

// ---------------- striped coalesced single-block scan ----------------
__device__ void scan_body(const int* __restrict__ deg, int* __restrict__ offs,
                          int* __restrict__ cursor, int n)
{
    __shared__ int wcarry[4];
    const int t = threadIdx.x;
    const int lane = t & 63;
    const int wid = t >> 6;
    int carry = 0;
    const int nstripes = (n + 1023) >> 10;
    for (int s = 0; s < nstripes; ++s) {
        const int base = (s << 10) + t * 4;
        int4 d = make_int4(0, 0, 0, 0);
        if (base + 3 < n) {
            d = *(const int4*)(deg + base);
        } else {
            if (base     < n) d.x = deg[base];
            if (base + 1 < n) d.y = deg[base + 1];
            if (base + 2 < n) d.z = deg[base + 2];
        }
        const int sum4 = (d.x + d.y) + (d.z + d.w);
        int inc = sum4;
#pragma unroll
        for (int o = 1; o < 64; o <<= 1) {
            int v = __shfl_up(inc, o, 64);
            if (lane >= o) inc += v;
        }
        if (lane == 63) wcarry[wid] = inc;
        __syncthreads();
        int wpre = carry;
#pragma unroll
        for (int k = 0; k < 4; ++k) if (k < wid) wpre += wcarry[k];
        const int e0 = wpre + inc - sum4;
        int4 ov;
        ov.x = e0; ov.y = e0 + d.x; ov.z = ov.y + d.y; ov.w = ov.z + d.z;
        if (base + 3 < n) {
            *(int4*)(offs + base) = ov;
            *(int4*)(cursor + base) = ov;
        } else {
            if (base     < n) { offs[base]     = ov.x; cursor[base]     = ov.x; }
            if (base + 1 < n) { offs[base + 1] = ov.y; cursor[base + 1] = ov.y; }
            if (base + 2 < n) { offs[base + 2] = ov.z; cursor[base + 2] = ov.z; }
        }
        carry += (wcarry[0] + wcarry[1]) + (wcarry[2] + wcarry[3]);
        __syncthreads();
    }
    if (t == 0) offs[n] = carry;
}

// ---------------- D2: proj_mfma (persistent) || scan ----------------
// 256 threads = 4 waves. Block tile: 64 rows x 272 cols, K=128 (R % 64 == 0).
// Blocks 0..PB-1 are persistent: load B-frags once, loop tiles b, b+PB, ...
__global__ __launch_bounds__(256) void proj_scan_kernel(
    const float* __restrict__ feat, const ushort* __restrict__ WT,
    ushort* __restrict__ ftb, float* __restrict__ el, float* __restrict__ er,
    const int* __restrict__ deg, int* __restrict__ offs, int* __restrict__ cursor,
    int N, int nTiles)
{
    const int PB = gridDim.x - 1;
    if ((int)blockIdx.x >= PB) {
        scan_body(deg, offs, cursor, N);
        return;
    }
    __shared__ ushort sxp[4][2][16][SXS];
    const int t = threadIdx.x;
    const int w = t >> 6;
    const int lane = t & 63;
    const int lr = lane & 15;
    const int lk = lane >> 4;

    // B fragments: loaded ONCE per block, reused across tiles
    short8v bfrag[4][4];
#pragma unroll
    for (int ct = 0; ct < 4; ++ct) {
        const int col = w * 64 + ct * 16 + lr;
#pragma unroll
        for (int ks = 0; ks < 4; ++ks)
            bfrag[ct][ks] = *(const short8v*)&WT[col * DIN + ks * 32 + lk * 8];
    }
    short8v efrag[4];
#pragma unroll
    for (int ks = 0; ks < 4; ++ks)
        efrag[ks] = *(const short8v*)&WT[(256 + lr) * DIN + ks * 32 + lk * 8];

    const int rrow = lane >> 2;
    const int seg  = lane & 3;

    for (int tile = blockIdx.x; tile < nTiles; tile += PB) {
        const int row0 = tile * 64;

        auto loadA = [&](int rt, short8v aout[4]) {
            const float* fp = feat + (size_t)(row0 + rt * 16 + lr) * DIN + lk * 8;
#pragma unroll
            for (int ks = 0; ks < 4; ++ks) {
                f32x4 x0 = *(const f32x4*)(fp + ks * 32);
                f32x4 x1 = *(const f32x4*)(fp + ks * 32 + 4);
                short8v v;
                v[0] = (short)f2bf(x0[0]); v[1] = (short)f2bf(x0[1]);
                v[2] = (short)f2bf(x0[2]); v[3] = (short)f2bf(x0[3]);
                v[4] = (short)f2bf(x1[0]); v[5] = (short)f2bf(x1[1]);
                v[6] = (short)f2bf(x1[2]); v[7] = (short)f2bf(x1[3]);
                aout[ks] = v;
            }
        };

        short8v aP[4], aN[4];
        loadA(0, aP);

#pragma unroll
        for (int rt = 0; rt < 4; ++rt) {
            if (rt < 3) loadA(rt + 1, aN);

            f32x4 acc[4] = {{0.f,0.f,0.f,0.f},{0.f,0.f,0.f,0.f},{0.f,0.f,0.f,0.f},{0.f,0.f,0.f,0.f}};
#pragma unroll
            for (int ct = 0; ct < 4; ++ct)
#pragma unroll
                for (int ks = 0; ks < 4; ++ks)
                    acc[ct] = __builtin_amdgcn_mfma_f32_16x16x32_bf16(aP[ks], bfrag[ct][ks], acc[ct], 0, 0, 0);

            ushort (* __restrict__ sw)[SXS] = sxp[w][rt & 1];
#pragma unroll
            for (int ct = 0; ct < 4; ++ct)
#pragma unroll
                for (int r = 0; r < 4; ++r)
                    sw[lk * 4 + r][ct * 16 + lr] = f2bf(acc[ct][r]);
            __builtin_amdgcn_wave_barrier();
            ushort8 o0 = *(const ushort8*)&sw[rrow][seg * 16];
            ushort8 o1 = *(const ushort8*)&sw[rrow][seg * 16 + 8];
            ushort* gp = ftb + (size_t)(row0 + rt * 16 + rrow) * HD + w * 64 + seg * 16;
            *(ushort8*)gp = o0;
            *(ushort8*)(gp + 8) = o1;

            if (rt == w) {  // extra tile: el/er columns (wave-uniform branch)
                f32x4 acce = {0.f, 0.f, 0.f, 0.f};
#pragma unroll
                for (int ks = 0; ks < 4; ++ks)
                    acce = __builtin_amdgcn_mfma_f32_16x16x32_bf16(aP[ks], efrag[ks], acce, 0, 0, 0);
#pragma unroll
                for (int r = 0; r < 4; ++r) {
                    const int row = row0 + rt * 16 + lk * 4 + r;
                    if (lr < 4)       el[row * 4 + lr]       = acce[r];
                    else if (lr < 8)  er[row * 4 + (lr - 4)] = acce[r];
                }
            }

#pragma unroll
            for (int ks = 0; ks < 4; ++ks) aP[ks] = aN[ks];
        }
    }
}

// ---------------- D3: scatter ----------------
__global__ __launch_bounds__(256) void scatter_kernel(
    const int* __restrict__ dst, const int* __restrict__ src,
    int* __restrict__ cursor, int* __restrict__ esrc, int E)
{
    int e4 = (blockIdx.x * 256 + threadIdx.x) * 4;
    if (e4 + 3 < E) {
        int4 dd = *(const int4*)(dst + e4);
        int4 ss = *(const int4*)(src + e4);
        int p0 = atomicAdd(&cursor[dd.x], 1); esrc[p0] = ss.x;
        int p1 = atomicAdd(&cursor[dd.y], 1); esrc[p1] = ss.y;
        int p2 = atomicAdd(&cursor[dd.z], 1); esrc[p2] = ss.z;
        int p3 = atomicAdd(&cursor[dd.w], 1); esrc[p3] = ss.w;
    } else {
        for (int e = e4; e < E; ++e) {
            int pos = atomicAdd(&cursor[dst[e]], 1);
            esrc[pos] = src[e];
        }
    }
}

// ---------------- D4: agg (R6 structure) ----------------
// One wave per dst node; lane covers cols 8*lane..8*lane+7 (ushort8 = 16B gather).
// Softmax denominator fused (no max-sub: |logit| <~ 7). Unroll 8; ftv loads issued
// before the el->exp chain so gathers overlap the weight computation.
__global__ __launch_bounds__(256) void agg_kernel(
    const ushort* __restrict__ ftb, const float* __restrict__ el,
    const float* __restrict__ er, const int* __restrict__ offs,
    const int* __restrict__ esrc, float* __restrict__ out, int N)
{
    const int t = threadIdx.x;
    const int n = blockIdx.x * 4 + (t >> 6);
    if (n >= N) return;
    const int lane = t & 63;
    const int bh = lane >> 3;
    const int beg = offs[n];
    const int end = offs[n + 1];

    const float erd = er[n * 8 + bh];
    const ushort8* __restrict__ ftv = (const ushort8*)ftb;

    float acc[8];
#pragma unroll
    for (int j = 0; j < 8; ++j) acc[j] = 0.f;
    float dsum = 0.f;

    int i = beg;
    for (; i + 7 < end; i += 8) {
        int s[8];
#pragma unroll
        for (int u = 0; u < 8; ++u) s[u] = esrc[i + u];
        ushort8 v[8];
#pragma unroll
        for (int u = 0; u < 8; ++u) v[u] = ftv[(unsigned)s[u] * 64 + lane];
        float w[8];
#pragma unroll
        for (int u = 0; u < 8; ++u) w[u] = __expf(leaky(el[s[u] * 8 + bh] + erd));
#pragma unroll
        for (int u = 0; u < 8; ++u) dsum += w[u];
#pragma unroll
        for (int j = 0; j < 8; ++j) {
            float a = acc[j];
#pragma unroll
            for (int u = 0; u < 8; ++u) a = fmaf(w[u], bf2f(v[u][j]), a);
            acc[j] = a;
        }
    }
    for (; i + 1 < end; i += 2) {
        int s0 = esrc[i], s1 = esrc[i + 1];
        ushort8 v0 = ftv[(unsigned)s0 * 64 + lane];
        ushort8 v1 = ftv[(unsigned)s1 * 64 + lane];
        float w0 = __expf(leaky(el[s0 * 8 + bh] + erd));
        float w1 = __expf(leaky(el[s1 * 8 + bh] + erd));
        dsum += w0 + w1;
#pragma unroll
        for (int j = 0; j < 8; ++j)
            acc[j] += w0 * bf2f(v0[j]) + w1 * bf2f(v1[j]);
    }
    if (i < end) {
        int s0 = esrc[i];
        ushort8 v0 = ftv[(unsigned)s0 * 64 + lane];
        float w0 = __expf(leaky(el[s0 * 8 + bh] + erd));
        dsum += w0;
#pragma unroll
        for (int j = 0; j < 8; ++j) acc[j] = fmaf(w0, bf2f(v0[j]), acc[j]);
    }

    const float sc = (end > beg) ? (1.f / dsum) : 0.f;
    float4 o0, o1;
    o0.x = leaky(acc[0] * sc); o0.y = leaky(acc[1] * sc);
    o0.z = leaky(acc[2] * sc); o0.w = leaky(acc[3] * sc);
    o1.x = leaky(acc[4] * sc); o1.y = leaky(acc[5] * sc);
    o1.z = leaky(acc[6] * sc); o1.w = leaky(acc[7] * sc);
    float* op = out + (size_t)n * BHD + lane * 8;
    *(float4*)op = o0;
    *(float4*)(op + 4) = o1;
}

extern "C" void kernel_launch(void* const* d_in, const int* in_sizes, int n_in,
                              void* d_out, int out_size, void* d_ws, size_t ws_size,
                              hipStream_t stream)
{
    const float* feat   = (const float*)d_in[0];
    const float* W      = (const float*)d_in[1];
    const float* attn_l = (const float*)d_in[2];
    const float* attn_r = (const float*)d_in[3];
    const int*   src    = (const int*)d_in[4];
    const int*   dst    = (const int*)d_in[5];
    float* out = (float*)d_out;

    const int N = in_sizes[0] / (B * DIN);
    const int E = in_sizes[4];
    const int R = N * B;
    const int nTiles = R / 64;                    // 625 for R=40000 (R % 64 == 0)
    const int projBlocks = (nTiles + 1) / 2;      // persistent: 2 tiles per block
    const int histBlocks = (E / 4 + 255) / 256;
    const int edgeBlocks = histBlocks;

    auto align_up = [](size_t x) { return (x + 255) & ~(size_t)255; };
    size_t off = 0;
    char* base = (char*)d_ws;
    ushort* ftb = (ushort*)(base + off); off += align_up((size_t)R * HD * sizeof(ushort));
    float* el   = (float*)(base + off); off += align_up((size_t)R * H * sizeof(float));
    float* er   = (float*)(base + off); off += align_up((size_t)R * H * sizeof(float));
    ushort* WT  = (ushort*)(base + off); off += align_up((size_t)NCOL * DIN * sizeof(ushort));
    int* deg    = (int*)(base + off); off += align_up((size_t)N * sizeof(int));
    int* offs   = (int*)(base + off); off += align_up((size_t)(N + 1) * sizeof(int));
    int* cursor = (int*)(base + off); off += align_up((size_t)N * sizeof(int));
    int* esrc   = (int*)(base + off); off += align_up((size_t)E * sizeof(int));
    (void)ws_size; (void)n_in; (void)out_size;

    hipMemsetAsync(deg, 0, (size_t)N * sizeof(int), stream);

    hist_prep_kernel<<<histBlocks + PREP_BLOCKS, 256, 0, stream>>>(
        dst, deg, E, W, attn_l, attn_r, WT, histBlocks);
    proj_scan_kernel<<<projBlocks + 1, 256, 0, stream>>>(
        feat, WT, ftb, el, er, deg, offs, cursor, N, nTiles);
    scatter_kernel<<<edgeBlocks, 256, 0, stream>>>(dst, src, cursor, esrc, E);
    agg_kernel<<<(N + 3) / 4, 256, 0, stream>>>(ftb, el, er, offs, esrc, out, N);
}

// Round 13
// 116.654 us; speedup vs baseline: 1.2747x; 1.0360x over previous
//
#include <hip/hip_runtime.h>
#include <hip/hip_bf16.h>
#include <math.h>

// BatchGATConv: N nodes, B=2 batches, DIN=128, H=4 heads, D=64, E edges.
// Dispatch plan (5 dispatches, scatter hidden under proj):
//   D0: memset deg
//   D1: hist (int4, 4 edges/thread) || prep WT          [independent]
//   D2: scan (single small block; needs only hist)
//   D3: proj_mfma (persistent) || scatter (block-range split; scatter needs only scan)
//   D4: agg (R6 structure: wave=node, 8-edge slots, full 512-dim row)

typedef unsigned short ushort;
typedef __attribute__((ext_vector_type(8))) unsigned short ushort8;
typedef __attribute__((ext_vector_type(8))) short short8v;
typedef __attribute__((ext_vector_type(4))) float f32x4;

constexpr int DIN = 128;
constexpr int B   = 2;
constexpr int H   = 4;
constexpr int D   = 64;
constexpr int HD  = H * D;      // 256
constexpr int BHD = B * HD;     // 512
constexpr int NCOL = 272;       // 256 + 16 (8 el/er cols + 8 zero pad)
constexpr int PREP_ELEMS  = NCOL * DIN;                 // 34816
constexpr int PREP_BLOCKS = (PREP_ELEMS + 255) / 256;   // 136
constexpr int SXS = 72;         // LDS transpose row stride (ushorts)

__device__ __forceinline__ float leaky(float x) { return x >= 0.f ? x : 0.2f * x; }

__device__ __forceinline__ ushort f2bf(float f) {
    return __builtin_bit_cast(ushort, __float2bfloat16(f));
}
__device__ __forceinline__ float bf2f(ushort v) {
    return __uint_as_float(((unsigned int)v) << 16);
}

// ---------------- D1: hist || prep ----------------
__global__ __launch_bounds__(256) void hist_prep_kernel(
    const int* __restrict__ dst, int* __restrict__ deg, int E,
    const float* __restrict__ W, const float* __restrict__ attn_l,
    const float* __restrict__ attn_r, ushort* __restrict__ WT, int histBlocks)
{
    const int t = threadIdx.x;
    const int b = blockIdx.x;
    if (b < histBlocks) {
        int e4 = (b * 256 + t) * 4;
        if (e4 + 3 < E) {
            int4 dd = *(const int4*)(dst + e4);
            atomicAdd(&deg[dd.x], 1); atomicAdd(&deg[dd.y], 1);
            atomicAdd(&deg[dd.z], 1); atomicAdd(&deg[dd.w], 1);
        } else {
            for (int e = e4; e < E; ++e) atomicAdd(&deg[dst[e]], 1);
        }
        return;
    }
    int id = (b - histBlocks) * 256 + t;
    if (id >= PREP_ELEMS) return;
    int c = id >> 7, k = id & 127;
    float v;
    if (c < 256) {
        v = W[k * HD + c];
    } else if (c < 264) {
        int j = c - 256, h = j & 3;
        const float* av = (j < 4 ? attn_l : attn_r) + h * D;
        const float* wp = W + k * HD + h * D;
        float s = 0.f;
        for (int d = 0; d < D; ++d) s = fmaf(wp[d], av[d], s);
        v = s;
    } else {
        v = 0.f;
    }
    WT[c * DIN + k] = f2bf(v);
}

// ---------------- D2: striped coalesced single-block scan ----------------
__global__ __launch_bounds__(256) void scan_kernel(
    const int* __restrict__ deg, int* __restrict__ offs,
    int* __restrict__ cursor, int n)
{
    __shared__ int wcarry[4];
    const int t = threadIdx.x;
    const int lane = t & 63;
    const int wid = t >> 6;
    int carry = 0;
    const int nstripes = (n + 1023) >> 10;
    for (int s = 0; s < nstripes; ++s) {
        const int base = (s << 10) + t * 4;
        int4 d = make_int4(0, 0, 0, 0);
        if (base + 3 < n) {
            d = *(const int4*)(deg + base);
        } else {
            if (base     < n) d.x = deg[base];
            if (base + 1 < n) d.y = deg[base + 1];
            if (base + 2 < n) d.z = deg[base + 2];
        }
        const int sum4 = (d.x + d.y) + (d.z + d.w);
        int inc = sum4;
#pragma unroll
        for (int o = 1; o < 64; o <<= 1) {
            int v = __shfl_up(inc, o, 64);
            if (lane >= o) inc += v;
        }
        if (lane == 63) wcarry[wid] = inc;
        __syncthreads();
        int wpre = carry;
#pragma unroll
        for (int k = 0; k < 4; ++k) if (k < wid) wpre += wcarry[k];
        const int e0 = wpre + inc - sum4;
        int4 ov;
        ov.x = e0; ov.y = e0 + d.x; ov.z = ov.y + d.y; ov.w = ov.z + d.z;
        if (base + 3 < n) {
            *(int4*)(offs + base) = ov;
            *(int4*)(cursor + base) = ov;
        } else {
            if (base     < n) { offs[base]     = ov.x; cursor[base]     = ov.x; }
            if (base + 1 < n) { offs[base + 1] = ov.y; cursor[base + 1] = ov.y; }
            if (base + 2 < n) { offs[base + 2] = ov.z; cursor[base + 2] = ov.z; }
        }
        carry += (wcarry[0] + wcarry[1]) + (wcarry[2] + wcarry[3]);
        __syncthreads();
    }
    if (t == 0) offs[n] = carry;
}

// ---------------- D3: proj_mfma (persistent) || scatter ----------------
// Blocks [0, PB): proj. Blocks [PB, PB+edgeBlocks): scatter (needs only scan's cursor).
__global__ __launch_bounds__(256) void proj_scatter_kernel(
    const float* __restrict__ feat, const ushort* __restrict__ WT,
    ushort* __restrict__ ftb, float* __restrict__ el, float* __restrict__ er,
    const int* __restrict__ dst, const int* __restrict__ src,
    int* __restrict__ cursor, int* __restrict__ esrc, int E,
    int nTiles, int PB)
{
    if ((int)blockIdx.x >= PB) {
        // ---- scatter part ----
        int e4 = (((int)blockIdx.x - PB) * 256 + (int)threadIdx.x) * 4;
        if (e4 + 3 < E) {
            int4 dd = *(const int4*)(dst + e4);
            int4 ss = *(const int4*)(src + e4);
            int p0 = atomicAdd(&cursor[dd.x], 1); esrc[p0] = ss.x;
            int p1 = atomicAdd(&cursor[dd.y], 1); esrc[p1] = ss.y;
            int p2 = atomicAdd(&cursor[dd.z], 1); esrc[p2] = ss.z;
            int p3 = atomicAdd(&cursor[dd.w], 1); esrc[p3] = ss.w;
        } else {
            for (int e = e4; e < E; ++e) {
                int pos = atomicAdd(&cursor[dst[e]], 1);
                esrc[pos] = src[e];
            }
        }
        return;
    }

    // ---- proj part (persistent over tiles) ----
    __shared__ ushort sxp[4][2][16][SXS];
    const int t = threadIdx.x;
    const int w = t >> 6;
    const int lane = t & 63;
    const int lr = lane & 15;
    const int lk = lane >> 4;

    short8v bfrag[4][4];
#pragma unroll
    for (int ct = 0; ct < 4; ++ct) {
        const int col = w * 64 + ct * 16 + lr;
#pragma unroll
        for (int ks = 0; ks < 4; ++ks)
            bfrag[ct][ks] = *(const short8v*)&WT[col * DIN + ks * 32 + lk * 8];
    }
    short8v efrag[4];
#pragma unroll
    for (int ks = 0; ks < 4; ++ks)
        efrag[ks] = *(const short8v*)&WT[(256 + lr) * DIN + ks * 32 + lk * 8];

    const int rrow = lane >> 2;
    const int seg  = lane & 3;

    for (int tile = blockIdx.x; tile < nTiles; tile += PB) {
        const int row0 = tile * 64;

        auto loadA = [&](int rt, short8v aout[4]) {
            const float* fp = feat + (size_t)(row0 + rt * 16 + lr) * DIN + lk * 8;
#pragma unroll
            for (int ks = 0; ks < 4; ++ks) {
                f32x4 x0 = *(const f32x4*)(fp + ks * 32);
                f32x4 x1 = *(const f32x4*)(fp + ks * 32 + 4);
                short8v v;
                v[0] = (short)f2bf(x0[0]); v[1] = (short)f2bf(x0[1]);
                v[2] = (short)f2bf(x0[2]); v[3] = (short)f2bf(x0[3]);
                v[4] = (short)f2bf(x1[0]); v[5] = (short)f2bf(x1[1]);
                v[6] = (short)f2bf(x1[2]); v[7] = (short)f2bf(x1[3]);
                aout[ks] = v;
            }
        };

        short8v aP[4], aN[4];
        loadA(0, aP);

#pragma unroll
        for (int rt = 0; rt < 4; ++rt) {
            if (rt < 3) loadA(rt + 1, aN);

            f32x4 acc[4] = {{0.f,0.f,0.f,0.f},{0.f,0.f,0.f,0.f},{0.f,0.f,0.f,0.f},{0.f,0.f,0.f,0.f}};
#pragma unroll
            for (int ct = 0; ct < 4; ++ct)
#pragma unroll
                for (int ks = 0; ks < 4; ++ks)
                    acc[ct] = __builtin_amdgcn_mfma_f32_16x16x32_bf16(aP[ks], bfrag[ct][ks], acc[ct], 0, 0, 0);

            ushort (* __restrict__ sw)[SXS] = sxp[w][rt & 1];
#pragma unroll
            for (int ct = 0; ct < 4; ++ct)
#pragma unroll
                for (int r = 0; r < 4; ++r)
                    sw[lk * 4 + r][ct * 16 + lr] = f2bf(acc[ct][r]);
            __builtin_amdgcn_wave_barrier();
            ushort8 o0 = *(const ushort8*)&sw[rrow][seg * 16];
            ushort8 o1 = *(const ushort8*)&sw[rrow][seg * 16 + 8];
            ushort* gp = ftb + (size_t)(row0 + rt * 16 + rrow) * HD + w * 64 + seg * 16;
            *(ushort8*)gp = o0;
            *(ushort8*)(gp + 8) = o1;

            if (rt == w) {  // extra tile: el/er columns (wave-uniform branch)
                f32x4 acce = {0.f, 0.f, 0.f, 0.f};
#pragma unroll
                for (int ks = 0; ks < 4; ++ks)
                    acce = __builtin_amdgcn_mfma_f32_16x16x32_bf16(aP[ks], efrag[ks], acce, 0, 0, 0);
#pragma unroll
                for (int r = 0; r < 4; ++r) {
                    const int row = row0 + rt * 16 + lk * 4 + r;
                    if (lr < 4)       el[row * 4 + lr]       = acce[r];
                    else if (lr < 8)  er[row * 4 + (lr - 4)] = acce[r];
                }
            }

#pragma unroll
            for (int ks = 0; ks < 4; ++ks) aP[ks] = aN[ks];
        }
    }
}

// ---------------- D4: agg (R6 structure) ----------------
// One wave per dst node; lane covers cols 8*lane..8*lane+7 (ushort8 = 16B gather).
// Softmax denominator fused (no max-sub: |logit| <~ 7). Unroll 8; ftv loads issued
// before the el->exp chain so gathers overlap the weight computation.
__global__ __launch_bounds__(256) void agg_kernel(
    const ushort* __restrict__ ftb, const float* __restrict__ el,
    const float* __restrict__ er, const int* __restrict__ offs,
    const int* __restrict__ esrc, float* __restrict__ out, int N)
{
    const int t = threadIdx.x;
    const int n = blockIdx.x * 4 + (t >> 6);
    if (n >= N) return;
    const int lane = t & 63;
    const int bh = lane >> 3;
    const int beg = offs[n];
    const int end = offs[n + 1];

    const float erd = er[n * 8 + bh];
    const ushort8* __restrict__ ftv = (const ushort8*)ftb;

    float acc[8];
#pragma unroll
    for (int j = 0; j < 8; ++j) acc[j] = 0.f;
    float dsum = 0.f;

    int i = beg;
    for (; i + 7 < end; i += 8) {
        int s[8];
#pragma unroll
        for (int u = 0; u < 8; ++u) s[u] = esrc[i + u];
        ushort8 v[8];
#pragma unroll
        for (int u = 0; u < 8; ++u) v[u] = ftv[(unsigned)s[u] * 64 + lane];
        float w[8];
#pragma unroll
        for (int u = 0; u < 8; ++u) w[u] = __expf(leaky(el[s[u] * 8 + bh] + erd));
#pragma unroll
        for (int u = 0; u < 8; ++u) dsum += w[u];
#pragma unroll
        for (int j = 0; j < 8; ++j) {
            float a = acc[j];
#pragma unroll
            for (int u = 0; u < 8; ++u) a = fmaf(w[u], bf2f(v[u][j]), a);
            acc[j] = a;
        }
    }
    for (; i + 1 < end; i += 2) {
        int s0 = esrc[i], s1 = esrc[i + 1];
        ushort8 v0 = ftv[(unsigned)s0 * 64 + lane];
        ushort8 v1 = ftv[(unsigned)s1 * 64 + lane];
        float w0 = __expf(leaky(el[s0 * 8 + bh] + erd));
        float w1 = __expf(leaky(el[s1 * 8 + bh] + erd));
        dsum += w0 + w1;
#pragma unroll
        for (int j = 0; j < 8; ++j)
            acc[j] += w0 * bf2f(v0[j]) + w1 * bf2f(v1[j]);
    }
    if (i < end) {
        int s0 = esrc[i];
        ushort8 v0 = ftv[(unsigned)s0 * 64 + lane];
        float w0 = __expf(leaky(el[s0 * 8 + bh] + erd));
        dsum += w0;
#pragma unroll
        for (int j = 0; j < 8; ++j) acc[j] = fmaf(w0, bf2f(v0[j]), acc[j]);
    }

    const float sc = (end > beg) ? (1.f / dsum) : 0.f;
    float4 o0, o1;
    o0.x = leaky(acc[0] * sc); o0.y = leaky(acc[1] * sc);
    o0.z = leaky(acc[2] * sc); o0.w = leaky(acc[3] * sc);
    o1.x = leaky(acc[4] * sc); o1.y = leaky(acc[5] * sc);
    o1.z = leaky(acc[6] * sc); o1.w = leaky(acc[7] * sc);
    float* op = out + (size_t)n * BHD + lane * 8;
    *(float4*)op = o0;
    *(float4*)(op + 4) = o1;
}

extern "C" void kernel_launch(void* const* d_in, const int* in_sizes, int n_in,
                              void* d_out, int out_size, void* d_ws, size_t ws_size,
                              hipStream_t stream)
{
    const float* feat   = (const float*)d_in[0];
    const float* W      = (const float*)d_in[1];
    const float* attn_l = (const float*)d_in[2];
    const float* attn_r = (const float*)d_in[3];
    const int*   src    = (const int*)d_in[4];
    const int*   dst    = (const int*)d_in[5];
    float* out = (float*)d_out;

    const int N = in_sizes[0] / (B * DIN);
    const int E = in_sizes[4];
    const int R = N * B;
    const int nTiles = R / 64;                    // 625 for R=40000 (R % 64 == 0)
    const int projBlocks = (nTiles + 1) / 2;      // persistent: 2 tiles per block
    const int histBlocks = (E / 4 + 255) / 256;
    const int edgeBlocks = histBlocks;

    auto align_up = [](size_t x) { return (x + 255) & ~(size_t)255; };
    size_t off = 0;
    char* base = (char*)d_ws;
    ushort* ftb = (ushort*)(base + off); off += align_up((size_t)R * HD * sizeof(ushort));
    float* el   = (float*)(base + off); off += align_up((size_t)R * H * sizeof(float));
    float* er   = (float*)(base + off); off += align_up((size_t)R * H * sizeof(float));
    ushort* WT  = (ushort*)(base + off); off += align_up((size_t)NCOL * DIN * sizeof(ushort));
    int* deg    = (int*)(base + off); off += align_up((size_t)N * sizeof(int));
    int* offs   = (int*)(base + off); off += align_up((size_t)(N + 1) * sizeof(int));
    int* cursor = (int*)(base + off); off += align_up((size_t)N * sizeof(int));
    int* esrc   = (int*)(base + off); off += align_up((size_t)E * sizeof(int));
    (void)ws_size; (void)n_in; (void)out_size;

    hipMemsetAsync(deg, 0, (size_t)N * sizeof(int), stream);

    hist_prep_kernel<<<histBlocks + PREP_BLOCKS, 256, 0, stream>>>(
        dst, deg, E, W, attn_l, attn_r, WT, histBlocks);
    scan_kernel<<<1, 256, 0, stream>>>(deg, offs, cursor, N);
    proj_scatter_kernel<<<projBlocks + edgeBlocks, 256, 0, stream>>>(
        feat, WT, ftb, el, er, dst, src, cursor, esrc, E, nTiles, projBlocks);
    agg_kernel<<<(N + 3) / 4, 256, 0, stream>>>(ftb, el, er, offs, esrc, out, N);
}

// Round 14
// 115.640 us; speedup vs baseline: 1.2859x; 1.0088x over previous
//
#include <hip/hip_runtime.h>
#include <hip/hip_bf16.h>
#include <math.h>

// BatchGATConv: N nodes, B=2 batches, DIN=128, H=4 heads, D=64, E edges.
// Dispatch plan (5 dispatches, scatter hidden under proj):
//   D0: memset deg
//   D1: hist (int4, 4 edges/thread) || prep WT          [independent]
//   D2: scan (single small block; needs only hist)
//   D3: proj_mfma (persistent) || scatter (block-range split; scatter needs only scan)
//   D4: agg (wave=node; width-4 depth-2 software-pipelined gather loop)

typedef unsigned short ushort;
typedef __attribute__((ext_vector_type(8))) unsigned short ushort8;
typedef __attribute__((ext_vector_type(8))) short short8v;
typedef __attribute__((ext_vector_type(4))) float f32x4;

constexpr int DIN = 128;
constexpr int B   = 2;
constexpr int H   = 4;
constexpr int D   = 64;
constexpr int HD  = H * D;      // 256
constexpr int BHD = B * HD;     // 512
constexpr int NCOL = 272;       // 256 + 16 (8 el/er cols + 8 zero pad)
constexpr int PREP_ELEMS  = NCOL * DIN;                 // 34816
constexpr int PREP_BLOCKS = (PREP_ELEMS + 255) / 256;   // 136
constexpr int SXS = 72;         // LDS transpose row stride (ushorts)

__device__ __forceinline__ float leaky(float x) { return x >= 0.f ? x : 0.2f * x; }

__device__ __forceinline__ ushort f2bf(float f) {
    return __builtin_bit_cast(ushort, __float2bfloat16(f));
}
__device__ __forceinline__ float bf2f(ushort v) {
    return __uint_as_float(((unsigned int)v) << 16);
}

// ---------------- D1: hist || prep ----------------
__global__ __launch_bounds__(256) void hist_prep_kernel(
    const int* __restrict__ dst, int* __restrict__ deg, int E,
    const float* __restrict__ W, const float* __restrict__ attn_l,
    const float* __restrict__ attn_r, ushort* __restrict__ WT, int histBlocks)
{
    const int t = threadIdx.x;
    const int b = blockIdx.x;
    if (b < histBlocks) {
        int e4 = (b * 256 + t) * 4;
        if (e4 + 3 < E) {
            int4 dd = *(const int4*)(dst + e4);
            atomicAdd(&deg[dd.x], 1); atomicAdd(&deg[dd.y], 1);
            atomicAdd(&deg[dd.z], 1); atomicAdd(&deg[dd.w], 1);
        } else {
            for (int e = e4; e < E; ++e) atomicAdd(&deg[dst[e]], 1);
        }
        return;
    }
    int id = (b - histBlocks) * 256 + t;
    if (id >= PREP_ELEMS) return;
    int c = id >> 7, k = id & 127;
    float v;
    if (c < 256) {
        v = W[k * HD + c];
    } else if (c < 264) {
        int j = c - 256, h = j & 3;
        const float* av = (j < 4 ? attn_l : attn_r) + h * D;
        const float* wp = W + k * HD + h * D;
        float s = 0.f;
        for (int d = 0; d < D; ++d) s = fmaf(wp[d], av[d], s);
        v = s;
    } else {
        v = 0.f;
    }
    WT[c * DIN + k] = f2bf(v);
}

// ---------------- D2: striped coalesced single-block scan ----------------
__global__ __launch_bounds__(256) void scan_kernel(
    const int* __restrict__ deg, int* __restrict__ offs,
    int* __restrict__ cursor, int n)
{
    __shared__ int wcarry[4];
    const int t = threadIdx.x;
    const int lane = t & 63;
    const int wid = t >> 6;
    int carry = 0;
    const int nstripes = (n + 1023) >> 10;
    for (int s = 0; s < nstripes; ++s) {
        const int base = (s << 10) + t * 4;
        int4 d = make_int4(0, 0, 0, 0);
        if (base + 3 < n) {
            d = *(const int4*)(deg + base);
        } else {
            if (base     < n) d.x = deg[base];
            if (base + 1 < n) d.y = deg[base + 1];
            if (base + 2 < n) d.z = deg[base + 2];
        }
        const int sum4 = (d.x + d.y) + (d.z + d.w);
        int inc = sum4;
#pragma unroll
        for (int o = 1; o < 64; o <<= 1) {
            int v = __shfl_up(inc, o, 64);
            if (lane >= o) inc += v;
        }
        if (lane == 63) wcarry[wid] = inc;
        __syncthreads();
        int wpre = carry;
#pragma unroll
        for (int k = 0; k < 4; ++k) if (k < wid) wpre += wcarry[k];
        const int e0 = wpre + inc - sum4;
        int4 ov;
        ov.x = e0; ov.y = e0 + d.x; ov.z = ov.y + d.y; ov.w = ov.z + d.z;
        if (base + 3 < n) {
            *(int4*)(offs + base) = ov;
            *(int4*)(cursor + base) = ov;
        } else {
            if (base     < n) { offs[base]     = ov.x; cursor[base]     = ov.x; }
            if (base + 1 < n) { offs[base + 1] = ov.y; cursor[base + 1] = ov.y; }
            if (base + 2 < n) { offs[base + 2] = ov.z; cursor[base + 2] = ov.z; }
        }
        carry += (wcarry[0] + wcarry[1]) + (wcarry[2] + wcarry[3]);
        __syncthreads();
    }
    if (t == 0) offs[n] = carry;
}

// ---------------- D3: proj_mfma (persistent) || scatter ----------------
__global__ __launch_bounds__(256) void proj_scatter_kernel(
    const float* __restrict__ feat, const ushort* __restrict__ WT,
    ushort* __restrict__ ftb, float* __restrict__ el, float* __restrict__ er,
    const int* __restrict__ dst, const int* __restrict__ src,
    int* __restrict__ cursor, int* __restrict__ esrc, int E,
    int nTiles, int PB)
{
    if ((int)blockIdx.x >= PB) {
        // ---- scatter part ----
        int e4 = (((int)blockIdx.x - PB) * 256 + (int)threadIdx.x) * 4;
        if (e4 + 3 < E) {
            int4 dd = *(const int4*)(dst + e4);
            int4 ss = *(const int4*)(src + e4);
            int p0 = atomicAdd(&cursor[dd.x], 1); esrc[p0] = ss.x;
            int p1 = atomicAdd(&cursor[dd.y], 1); esrc[p1] = ss.y;
            int p2 = atomicAdd(&cursor[dd.z], 1); esrc[p2] = ss.z;
            int p3 = atomicAdd(&cursor[dd.w], 1); esrc[p3] = ss.w;
        } else {
            for (int e = e4; e < E; ++e) {
                int pos = atomicAdd(&cursor[dst[e]], 1);
                esrc[pos] = src[e];
            }
        }
        return;
    }

    // ---- proj part (persistent over tiles) ----
    __shared__ ushort sxp[4][2][16][SXS];
    const int t = threadIdx.x;
    const int w = t >> 6;
    const int lane = t & 63;
    const int lr = lane & 15;
    const int lk = lane >> 4;

    short8v bfrag[4][4];
#pragma unroll
    for (int ct = 0; ct < 4; ++ct) {
        const int col = w * 64 + ct * 16 + lr;
#pragma unroll
        for (int ks = 0; ks < 4; ++ks)
            bfrag[ct][ks] = *(const short8v*)&WT[col * DIN + ks * 32 + lk * 8];
    }
    short8v efrag[4];
#pragma unroll
    for (int ks = 0; ks < 4; ++ks)
        efrag[ks] = *(const short8v*)&WT[(256 + lr) * DIN + ks * 32 + lk * 8];

    const int rrow = lane >> 2;
    const int seg  = lane & 3;

    for (int tile = blockIdx.x; tile < nTiles; tile += PB) {
        const int row0 = tile * 64;

        auto loadA = [&](int rt, short8v aout[4]) {
            const float* fp = feat + (size_t)(row0 + rt * 16 + lr) * DIN + lk * 8;
#pragma unroll
            for (int ks = 0; ks < 4; ++ks) {
                f32x4 x0 = *(const f32x4*)(fp + ks * 32);
                f32x4 x1 = *(const f32x4*)(fp + ks * 32 + 4);
                short8v v;
                v[0] = (short)f2bf(x0[0]); v[1] = (short)f2bf(x0[1]);
                v[2] = (short)f2bf(x0[2]); v[3] = (short)f2bf(x0[3]);
                v[4] = (short)f2bf(x1[0]); v[5] = (short)f2bf(x1[1]);
                v[6] = (short)f2bf(x1[2]); v[7] = (short)f2bf(x1[3]);
                aout[ks] = v;
            }
        };

        short8v aP[4], aN[4];
        loadA(0, aP);

#pragma unroll
        for (int rt = 0; rt < 4; ++rt) {
            if (rt < 3) loadA(rt + 1, aN);

            f32x4 acc[4] = {{0.f,0.f,0.f,0.f},{0.f,0.f,0.f,0.f},{0.f,0.f,0.f,0.f},{0.f,0.f,0.f,0.f}};
#pragma unroll
            for (int ct = 0; ct < 4; ++ct)
#pragma unroll
                for (int ks = 0; ks < 4; ++ks)
                    acc[ct] = __builtin_amdgcn_mfma_f32_16x16x32_bf16(aP[ks], bfrag[ct][ks], acc[ct], 0, 0, 0);

            ushort (* __restrict__ sw)[SXS] = sxp[w][rt & 1];
#pragma unroll
            for (int ct = 0; ct < 4; ++ct)
#pragma unroll
                for (int r = 0; r < 4; ++r)
                    sw[lk * 4 + r][ct * 16 + lr] = f2bf(acc[ct][r]);
            __builtin_amdgcn_wave_barrier();
            ushort8 o0 = *(const ushort8*)&sw[rrow][seg * 16];
            ushort8 o1 = *(const ushort8*)&sw[rrow][seg * 16 + 8];
            ushort* gp = ftb + (size_t)(row0 + rt * 16 + rrow) * HD + w * 64 + seg * 16;
            *(ushort8*)gp = o0;
            *(ushort8*)(gp + 8) = o1;

            if (rt == w) {  // extra tile: el/er columns (wave-uniform branch)
                f32x4 acce = {0.f, 0.f, 0.f, 0.f};
#pragma unroll
                for (int ks = 0; ks < 4; ++ks)
                    acce = __builtin_amdgcn_mfma_f32_16x16x32_bf16(aP[ks], efrag[ks], acce, 0, 0, 0);
#pragma unroll
                for (int r = 0; r < 4; ++r) {
                    const int row = row0 + rt * 16 + lk * 4 + r;
                    if (lr < 4)       el[row * 4 + lr]       = acce[r];
                    else if (lr < 8)  er[row * 4 + (lr - 4)] = acce[r];
                }
            }

#pragma unroll
            for (int ks = 0; ks < 4; ++ks) aP[ks] = aN[ks];
        }
    }
}

// ---------------- D4: agg (software-pipelined gather) ----------------
// One wave per dst node; lane covers cols 8*lane..8*lane+7 (ushort8 = 16B gather).
// Width-4 depth-2 pipeline: next stage's esrc/ftv/el loads issue before current
// stage's exp+FMA work, hiding the dependent gather latency chain.
__global__ __launch_bounds__(256) void agg_kernel(
    const ushort* __restrict__ ftb, const float* __restrict__ el,
    const float* __restrict__ er, const int* __restrict__ offs,
    const int* __restrict__ esrc, float* __restrict__ out, int N)
{
    const int t = threadIdx.x;
    const int n = blockIdx.x * 4 + (t >> 6);
    if (n >= N) return;
    const int lane = t & 63;
    const int bh = lane >> 3;
    const int beg = offs[n];
    const int end = offs[n + 1];

    const float erd = er[n * 8 + bh];
    const ushort8* __restrict__ ftv = (const ushort8*)ftb;

    float acc[8];
#pragma unroll
    for (int j = 0; j < 8; ++j) acc[j] = 0.f;
    float dsum = 0.f;

    int i = beg;
    if (end - beg >= 8) {
        // prologue: load stage A covering [i, i+4)
        int sA[4]; ushort8 vA[4]; float xA[4];
#pragma unroll
        for (int u = 0; u < 4; ++u) sA[u] = esrc[i + u];
#pragma unroll
        for (int u = 0; u < 4; ++u) vA[u] = ftv[(unsigned)sA[u] * 64 + lane];
#pragma unroll
        for (int u = 0; u < 4; ++u) xA[u] = el[sA[u] * 8 + bh];

        for (; i + 7 < end; i += 4) {
            // issue stage B loads [i+4, i+8) before touching stage A's data
            int sB[4]; ushort8 vB[4]; float xB[4];
#pragma unroll
            for (int u = 0; u < 4; ++u) sB[u] = esrc[i + 4 + u];
#pragma unroll
            for (int u = 0; u < 4; ++u) vB[u] = ftv[(unsigned)sB[u] * 64 + lane];
#pragma unroll
            for (int u = 0; u < 4; ++u) xB[u] = el[sB[u] * 8 + bh];

            // compute stage A
            float w[4];
#pragma unroll
            for (int u = 0; u < 4; ++u) { w[u] = __expf(leaky(xA[u] + erd)); }
            dsum += (w[0] + w[1]) + (w[2] + w[3]);
#pragma unroll
            for (int j = 0; j < 8; ++j) {
                float a = acc[j];
#pragma unroll
                for (int u = 0; u < 4; ++u) a = fmaf(w[u], bf2f(vA[u][j]), a);
                acc[j] = a;
            }
            // rotate B -> A
#pragma unroll
            for (int u = 0; u < 4; ++u) { sA[u] = sB[u]; vA[u] = vB[u]; xA[u] = xB[u]; }
        }
        // drain stage A ([i, i+4) still loaded and valid)
        float w[4];
#pragma unroll
        for (int u = 0; u < 4; ++u) { w[u] = __expf(leaky(xA[u] + erd)); }
        dsum += (w[0] + w[1]) + (w[2] + w[3]);
#pragma unroll
        for (int j = 0; j < 8; ++j) {
            float a = acc[j];
#pragma unroll
            for (int u = 0; u < 4; ++u) a = fmaf(w[u], bf2f(vA[u][j]), a);
            acc[j] = a;
        }
        i += 4;
    }
    // scalar tail (<= 7 edges)
    for (; i < end; ++i) {
        int s0 = esrc[i];
        ushort8 v0 = ftv[(unsigned)s0 * 64 + lane];
        float w0 = __expf(leaky(el[s0 * 8 + bh] + erd));
        dsum += w0;
#pragma unroll
        for (int j = 0; j < 8; ++j) acc[j] = fmaf(w0, bf2f(v0[j]), acc[j]);
    }

    const float sc = (end > beg) ? (1.f / dsum) : 0.f;
    float4 o0, o1;
    o0.x = leaky(acc[0] * sc); o0.y = leaky(acc[1] * sc);
    o0.z = leaky(acc[2] * sc); o0.w = leaky(acc[3] * sc);
    o1.x = leaky(acc[4] * sc); o1.y = leaky(acc[5] * sc);
    o1.z = leaky(acc[6] * sc); o1.w = leaky(acc[7] * sc);
    float* op = out + (size_t)n * BHD + lane * 8;
    *(float4*)op = o0;
    *(float4*)(op + 4) = o1;
}

extern "C" void kernel_launch(void* const* d_in, const int* in_sizes, int n_in,
                              void* d_out, int out_size, void* d_ws, size_t ws_size,
                              hipStream_t stream)
{
    const float* feat   = (const float*)d_in[0];
    const float* W      = (const float*)d_in[1];
    const float* attn_l = (const float*)d_in[2];
    const float* attn_r = (const float*)d_in[3];
    const int*   src    = (const int*)d_in[4];
    const int*   dst    = (const int*)d_in[5];
    float* out = (float*)d_out;

    const int N = in_sizes[0] / (B * DIN);
    const int E = in_sizes[4];
    const int R = N * B;
    const int nTiles = R / 64;                    // 625 for R=40000 (R % 64 == 0)
    const int projBlocks = (nTiles + 1) / 2;      // persistent: 2 tiles per block
    const int histBlocks = (E / 4 + 255) / 256;
    const int edgeBlocks = histBlocks;

    auto align_up = [](size_t x) { return (x + 255) & ~(size_t)255; };
    size_t off = 0;
    char* base = (char*)d_ws;
    ushort* ftb = (ushort*)(base + off); off += align_up((size_t)R * HD * sizeof(ushort));
    float* el   = (float*)(base + off); off += align_up((size_t)R * H * sizeof(float));
    float* er   = (float*)(base + off); off += align_up((size_t)R * H * sizeof(float));
    ushort* WT  = (ushort*)(base + off); off += align_up((size_t)NCOL * DIN * sizeof(ushort));
    int* deg    = (int*)(base + off); off += align_up((size_t)N * sizeof(int));
    int* offs   = (int*)(base + off); off += align_up((size_t)(N + 1) * sizeof(int));
    int* cursor = (int*)(base + off); off += align_up((size_t)N * sizeof(int));
    int* esrc   = (int*)(base + off); off += align_up((size_t)E * sizeof(int));
    (void)ws_size; (void)n_in; (void)out_size;

    hipMemsetAsync(deg, 0, (size_t)N * sizeof(int), stream);

    hist_prep_kernel<<<histBlocks + PREP_BLOCKS, 256, 0, stream>>>(
        dst, deg, E, W, attn_l, attn_r, WT, histBlocks);
    scan_kernel<<<1, 256, 0, stream>>>(deg, offs, cursor, N);
    proj_scatter_kernel<<<projBlocks + edgeBlocks, 256, 0, stream>>>(
        feat, WT, ftb, el, er, dst, src, cursor, esrc, E, nTiles, projBlocks);
    agg_kernel<<<(N + 3) / 4, 256, 0, stream>>>(ftb, el, er, offs, esrc, out, N);
}